// Round 1
// baseline (1561.666 us; speedup 1.0000x reference)
//
#include <hip/hip_runtime.h>
#include <math.h>

#define NUM_ROIS 32
#define REG_PER_ROI 50   // 1 + 4 + 9 + 36
#define FH 96
#define FW 96
#define FC 512
#define FB 16
#define NREG (NUM_ROIS * REG_PER_ROI)   // 1600

// One block per (region, batch). 128 threads; thread t owns channels [4t, 4t+4)
// as a float4 -> 128 * 16B = 2KB coalesced per pixel.
__global__ __launch_bounds__(128)
void RoiPooling_33440615366842_kernel(const float* __restrict__ fm,
                                      const int* __restrict__ rois,
                                      float* __restrict__ out)
{
    const int r = blockIdx.x;   // 0..1599 global region index
    const int b = blockIdx.y;   // 0..15 batch

    const int roi = r / REG_PER_ROI;
    const int s   = r % REG_PER_ROI;

    // region s -> pool level p and (ix, jy); append order was: for ix: for jy
    int p, base;
    if (s < 1)       { p = 1; base = 0; }
    else if (s < 5)  { p = 2; base = 1; }
    else if (s < 14) { p = 3; base = 5; }
    else             { p = 6; base = 14; }
    const int local = s - base;
    const int ix = local / p;
    const int jy = local % p;

    const int rx = rois[roi * 4 + 0];
    const int ry = rois[roi * 4 + 1];
    const int rw = rois[roi * 4 + 2];
    const int rh = rois[roi * 4 + 3];

    // NOTE: reference uses cl = h/p for the X bounds and rl = w/p for the Y
    // bounds (intentional replication of the reference's axis swap).
    const double cl = (double)rh / (double)p;
    const double rl = (double)rw / (double)p;
    const double xd = (double)rx;
    const double yd = (double)ry;

    // Python round() == rint (round-half-even) on doubles.
    const int x1 = (int)rint(xd + (double)ix * cl);
    const int x2 = (int)rint(xd + (double)ix * cl + cl);
    const int y1 = (int)rint(yd + (double)jy * rl);
    const int y2 = (int)rint(yd + (double)jy * rl + rl);

    const int c4 = threadIdx.x;  // 0..127
    const float4* __restrict__ fm4 = (const float4*)fm;

    float4 m = make_float4(-INFINITY, -INFINITY, -INFINITY, -INFINITY);
    for (int y = y1; y < y2; ++y) {
        const float4* __restrict__ row = fm4 + (size_t)(b * FH + y) * FW * (FC / 4);
        for (int x = x1; x < x2; ++x) {
            float4 v = row[(size_t)x * (FC / 4) + c4];
            m.x = fmaxf(m.x, v.x);
            m.y = fmaxf(m.y, v.y);
            m.z = fmaxf(m.z, v.z);
            m.w = fmaxf(m.w, v.w);
        }
    }

    float4* out4 = (float4*)out;
    out4[((size_t)b * NREG + r) * (FC / 4) + c4] = m;
}

extern "C" void kernel_launch(void* const* d_in, const int* in_sizes, int n_in,
                              void* d_out, int out_size, void* d_ws, size_t ws_size,
                              hipStream_t stream) {
    const float* fm   = (const float*)d_in[0];
    const int*   rois = (const int*)d_in[1];
    float*       out  = (float*)d_out;

    dim3 grid(NREG, FB);
    dim3 block(128);
    RoiPooling_33440615366842_kernel<<<grid, block, 0, stream>>>(fm, rois, out);
}

// Round 2
// 821.022 us; speedup vs baseline: 1.9021x; 1.9021x over previous
//
#include <hip/hip_runtime.h>
#include <math.h>

#define NUM_ROIS 32
#define REG_PER_ROI 50   // 1 + 4 + 9 + 36
#define FH 96
#define FW 96
#define FC 512
#define FC4 (FC / 4)     // 128 float4 per pixel
#define FB 16
#define NREG (NUM_ROIS * REG_PER_ROI)   // 1600
#define RPB 49           // regions computed per roi by kernel1 (s=1..49)

// Kernel 1: one block per (region s=1..49, batch). 128 threads; thread t owns
// channels [4t,4t+4) as float4. x-loop unrolled x4 with 4 independent
// accumulators -> 4 loads in flight per thread (latency hiding).
__global__ __launch_bounds__(128)
void roi_pool_levels(const float* __restrict__ fm,
                     const int* __restrict__ rois,
                     float* __restrict__ out)
{
    const int r = blockIdx.x;            // 0..(32*49-1)
    const int b = blockIdx.y;            // 0..15

    const int roi = r / RPB;
    const int s   = 1 + (r % RPB);       // skip s==0 (computed by kernel 2)

    int p, base;
    if (s < 5)       { p = 2; base = 1; }
    else if (s < 14) { p = 3; base = 5; }
    else             { p = 6; base = 14; }
    const int local = s - base;
    const int ix = local / p;
    const int jy = local % p;

    const int rx = rois[roi * 4 + 0];
    const int ry = rois[roi * 4 + 1];
    const int rw = rois[roi * 4 + 2];
    const int rh = rois[roi * 4 + 3];

    // Reference's axis swap replicated: cl=h/p drives X, rl=w/p drives Y.
    const double cl = (double)rh / (double)p;
    const double rl = (double)rw / (double)p;
    const double xd = (double)rx;
    const double yd = (double)ry;

    const int x1 = (int)rint(xd + (double)ix * cl);
    const int x2 = (int)rint(xd + (double)ix * cl + cl);
    const int y1 = (int)rint(yd + (double)jy * rl);
    const int y2 = (int)rint(yd + (double)jy * rl + rl);

    const int c4 = threadIdx.x;
    const float4* __restrict__ fm4 = (const float4*)fm;

    float4 m0 = make_float4(-INFINITY, -INFINITY, -INFINITY, -INFINITY);
    float4 m1 = m0, m2 = m0, m3 = m0;

    const int n = x2 - x1;
    for (int y = y1; y < y2; ++y) {
        const float4* __restrict__ pix =
            fm4 + ((size_t)(b * FH + y) * FW + x1) * FC4 + c4;
        int x = 0;
        for (; x + 4 <= n; x += 4) {
            float4 v0 = pix[(size_t)(x + 0) * FC4];
            float4 v1 = pix[(size_t)(x + 1) * FC4];
            float4 v2 = pix[(size_t)(x + 2) * FC4];
            float4 v3 = pix[(size_t)(x + 3) * FC4];
            m0.x = fmaxf(m0.x, v0.x); m0.y = fmaxf(m0.y, v0.y);
            m0.z = fmaxf(m0.z, v0.z); m0.w = fmaxf(m0.w, v0.w);
            m1.x = fmaxf(m1.x, v1.x); m1.y = fmaxf(m1.y, v1.y);
            m1.z = fmaxf(m1.z, v1.z); m1.w = fmaxf(m1.w, v1.w);
            m2.x = fmaxf(m2.x, v2.x); m2.y = fmaxf(m2.y, v2.y);
            m2.z = fmaxf(m2.z, v2.z); m2.w = fmaxf(m2.w, v2.w);
            m3.x = fmaxf(m3.x, v3.x); m3.y = fmaxf(m3.y, v3.y);
            m3.z = fmaxf(m3.z, v3.z); m3.w = fmaxf(m3.w, v3.w);
        }
        for (; x < n; ++x) {
            float4 v = pix[(size_t)x * FC4];
            m0.x = fmaxf(m0.x, v.x); m0.y = fmaxf(m0.y, v.y);
            m0.z = fmaxf(m0.z, v.z); m0.w = fmaxf(m0.w, v.w);
        }
    }

    m0.x = fmaxf(fmaxf(m0.x, m1.x), fmaxf(m2.x, m3.x));
    m0.y = fmaxf(fmaxf(m0.y, m1.y), fmaxf(m2.y, m3.y));
    m0.z = fmaxf(fmaxf(m0.z, m1.z), fmaxf(m2.z, m3.z));
    m0.w = fmaxf(fmaxf(m0.w, m1.w), fmaxf(m2.w, m3.w));

    float4* out4 = (float4*)out;
    out4[((size_t)b * NREG + roi * REG_PER_ROI + s) * FC4 + c4] = m0;
}

// Kernel 2: s==0 (p=1, whole footprint) == max of the four p=2 bins, which
// tile the footprint EXACTLY (h/2, w/2 exact in binary; shared boundaries are
// the identical double expression rint(x+cl)).
__global__ __launch_bounds__(128)
void roi_pool_level0(float* __restrict__ out)
{
    const int roi = blockIdx.x;
    const int b   = blockIdx.y;
    const int c4  = threadIdx.x;

    float4* out4 = (float4*)out;
    const size_t base = ((size_t)b * NREG + roi * REG_PER_ROI) * FC4 + c4;

    float4 a = out4[base + 1 * FC4];
    float4 c = out4[base + 2 * FC4];
    float4 d = out4[base + 3 * FC4];
    float4 e = out4[base + 4 * FC4];

    float4 m;
    m.x = fmaxf(fmaxf(a.x, c.x), fmaxf(d.x, e.x));
    m.y = fmaxf(fmaxf(a.y, c.y), fmaxf(d.y, e.y));
    m.z = fmaxf(fmaxf(a.z, c.z), fmaxf(d.z, e.z));
    m.w = fmaxf(fmaxf(a.w, c.w), fmaxf(d.w, e.w));

    out4[base] = m;
}

extern "C" void kernel_launch(void* const* d_in, const int* in_sizes, int n_in,
                              void* d_out, int out_size, void* d_ws, size_t ws_size,
                              hipStream_t stream) {
    const float* fm   = (const float*)d_in[0];
    const int*   rois = (const int*)d_in[1];
    float*       out  = (float*)d_out;

    dim3 grid1(NUM_ROIS * RPB, FB);
    roi_pool_levels<<<grid1, dim3(128), 0, stream>>>(fm, rois, out);

    dim3 grid2(NUM_ROIS, FB);
    roi_pool_level0<<<grid2, dim3(128), 0, stream>>>(out);
}

// Round 3
// 782.283 us; speedup vs baseline: 1.9963x; 1.0495x over previous
//
#include <hip/hip_runtime.h>
#include <math.h>

#define NUM_ROIS 32
#define REG_PER_ROI 50   // 1 + 4 + 9 + 36
#define FH 96
#define FW 96
#define FC 512
#define FC4 (FC / 4)     // 128 float4 per pixel
#define FB 16
#define NREG (NUM_ROIS * REG_PER_ROI)   // 1600
#define RPB 49           // regions computed per roi by kernel1 (s=1..49)

// Kernel 1: one block per (bin s=1..49, batch). 128 threads; thread t owns
// channels [4t,4t+4) as one float4. The bin's 2D pixel range is flattened to
// a 1D loop with 8 independent slots -> 8 loads always in flight per thread,
// even for tiny p=6 bins. Slot coordinates are wave-uniform (SALU); lanes
// only execute the fmax chain.
__global__ __launch_bounds__(128)
void roi_pool_levels(const float* __restrict__ fm,
                     const int* __restrict__ rois,
                     float* __restrict__ out)
{
    const int r = blockIdx.x;            // 0..(32*49-1)
    const int b = blockIdx.y;            // 0..15

    const int roi = r / RPB;
    const int s   = 1 + (r % RPB);       // skip s==0 (derived by kernel 2)

    int p, base;
    if (s < 5)       { p = 2; base = 1; }
    else if (s < 14) { p = 3; base = 5; }
    else             { p = 6; base = 14; }
    const int local = s - base;
    const int ix = local / p;
    const int jy = local % p;

    // Force scalar (wave-uniform) roi fields so all bin math lives on SALU.
    const int rx = __builtin_amdgcn_readfirstlane(rois[roi * 4 + 0]);
    const int ry = __builtin_amdgcn_readfirstlane(rois[roi * 4 + 1]);
    const int rw = __builtin_amdgcn_readfirstlane(rois[roi * 4 + 2]);
    const int rh = __builtin_amdgcn_readfirstlane(rois[roi * 4 + 3]);

    // Reference's axis swap replicated: cl=h/p drives X, rl=w/p drives Y.
    // Python round() == rint (round-half-even) on doubles.
    const double cl = (double)rh / (double)p;
    const double rl = (double)rw / (double)p;
    const double xd = (double)rx;
    const double yd = (double)ry;

    const int x1 = (int)rint(xd + (double)ix * cl);
    const int x2 = (int)rint(xd + (double)ix * cl + cl);
    const int y1 = (int)rint(yd + (double)jy * rl);
    const int y2 = (int)rint(yd + (double)jy * rl + rl);

    const int spanx = x2 - x1;
    const int n = spanx * (y2 - y1);     // >= 1 always (cl,rl >= 8/6)

    const int c4 = threadIdx.x;
    const float4* __restrict__ fmb =
        (const float4*)fm + (size_t)b * FH * FW * FC4 + c4;

    // Slot s0 walks flat indices s0, s0+8, s0+16, ...
    int xs[8], ys[8];
    {
        int xx = x1, yy = y1;
#pragma unroll
        for (int s0 = 0; s0 < 8; ++s0) {
            xs[s0] = xx; ys[s0] = yy;
            if (++xx == x2) { xx = x1; ++yy; }
        }
    }

    const float4 ninf = make_float4(-INFINITY, -INFINITY, -INFINITY, -INFINITY);
    float4 acc[8] = {ninf, ninf, ninf, ninf, ninf, ninf, ninf, ninf};

    int i = 0;
    for (; i + 8 <= n; i += 8) {
        float4 v[8];
#pragma unroll
        for (int s0 = 0; s0 < 8; ++s0)
            v[s0] = fmb[(size_t)(ys[s0] * FW + xs[s0]) * FC4];
#pragma unroll
        for (int s0 = 0; s0 < 8; ++s0) {
            acc[s0].x = fmaxf(acc[s0].x, v[s0].x);
            acc[s0].y = fmaxf(acc[s0].y, v[s0].y);
            acc[s0].z = fmaxf(acc[s0].z, v[s0].z);
            acc[s0].w = fmaxf(acc[s0].w, v[s0].w);
        }
#pragma unroll
        for (int s0 = 0; s0 < 8; ++s0) {
            xs[s0] += 8;
            while (xs[s0] >= x2) { xs[s0] -= spanx; ++ys[s0]; }
        }
    }
    // Tail: slots 0..(n-i-1) sit exactly at flat indices i..n-1.
#pragma unroll
    for (int s0 = 0; s0 < 8; ++s0) {
        if (s0 < n - i) {
            float4 v = fmb[(size_t)(ys[s0] * FW + xs[s0]) * FC4];
            acc[s0].x = fmaxf(acc[s0].x, v.x);
            acc[s0].y = fmaxf(acc[s0].y, v.y);
            acc[s0].z = fmaxf(acc[s0].z, v.z);
            acc[s0].w = fmaxf(acc[s0].w, v.w);
        }
    }

#pragma unroll
    for (int s0 = 4; s0 < 8; ++s0) {
        acc[s0 - 4].x = fmaxf(acc[s0 - 4].x, acc[s0].x);
        acc[s0 - 4].y = fmaxf(acc[s0 - 4].y, acc[s0].y);
        acc[s0 - 4].z = fmaxf(acc[s0 - 4].z, acc[s0].z);
        acc[s0 - 4].w = fmaxf(acc[s0 - 4].w, acc[s0].w);
    }
    float4 m;
    m.x = fmaxf(fmaxf(acc[0].x, acc[1].x), fmaxf(acc[2].x, acc[3].x));
    m.y = fmaxf(fmaxf(acc[0].y, acc[1].y), fmaxf(acc[2].y, acc[3].y));
    m.z = fmaxf(fmaxf(acc[0].z, acc[1].z), fmaxf(acc[2].z, acc[3].z));
    m.w = fmaxf(fmaxf(acc[0].w, acc[1].w), fmaxf(acc[2].w, acc[3].w));

    float4* out4 = (float4*)out;
    out4[((size_t)b * NREG + roi * REG_PER_ROI + s) * FC4 + c4] = m;
}

// Kernel 2: s==0 (p=1, whole footprint) == max of the four p=2 bins, which
// tile the footprint EXACTLY (h/2, w/2 exact in binary; shared boundaries are
// the identical double expression rint(x+cl)).
__global__ __launch_bounds__(128)
void roi_pool_level0(float* __restrict__ out)
{
    const int roi = blockIdx.x;
    const int b   = blockIdx.y;
    const int c4  = threadIdx.x;

    float4* out4 = (float4*)out;
    const size_t base = ((size_t)b * NREG + roi * REG_PER_ROI) * FC4 + c4;

    float4 a = out4[base + 1 * FC4];
    float4 c = out4[base + 2 * FC4];
    float4 d = out4[base + 3 * FC4];
    float4 e = out4[base + 4 * FC4];

    float4 m;
    m.x = fmaxf(fmaxf(a.x, c.x), fmaxf(d.x, e.x));
    m.y = fmaxf(fmaxf(a.y, c.y), fmaxf(d.y, e.y));
    m.z = fmaxf(fmaxf(a.z, c.z), fmaxf(d.z, e.z));
    m.w = fmaxf(fmaxf(a.w, c.w), fmaxf(d.w, e.w));

    out4[base] = m;
}

extern "C" void kernel_launch(void* const* d_in, const int* in_sizes, int n_in,
                              void* d_out, int out_size, void* d_ws, size_t ws_size,
                              hipStream_t stream) {
    const float* fm   = (const float*)d_in[0];
    const int*   rois = (const int*)d_in[1];
    float*       out  = (float*)d_out;

    dim3 grid1(NUM_ROIS * RPB, FB);
    roi_pool_levels<<<grid1, dim3(128), 0, stream>>>(fm, rois, out);

    dim3 grid2(NUM_ROIS, FB);
    roi_pool_level0<<<grid2, dim3(128), 0, stream>>>(out);
}

// Round 4
// 772.880 us; speedup vs baseline: 2.0206x; 1.0122x over previous
//
#include <hip/hip_runtime.h>
#include <math.h>

#define NUM_ROIS 32
#define REG_PER_ROI 50   // 1 + 4 + 9 + 36
#define FH 96
#define FW 96
#define FC 512
#define FC4 (FC / 4)     // 128 float4 per pixel
#define FB 16
#define NREG (NUM_ROIS * REG_PER_ROI)   // 1600
#define RPB 49           // regions computed per roi by kernel1 (s=1..49)

// Kernel 1: one block per (bin s=1..49, batch). 128 threads; thread t owns
// channels [4t,4t+4) as one float4. Flat 1D pixel walk with 8 slots; the 8
// loads per iteration are issued from ONE inline-asm block (8x
// global_load_dwordx4 then s_waitcnt vmcnt(0)) so the compiler CANNOT
// collapse them into a serial load->max chain (R2/R3 showed it does:
// VGPR_Count=36 => ~1 outstanding load => ~1160 cy/iter latency-bound).
__global__ __launch_bounds__(128)
void roi_pool_levels(const float* __restrict__ fm,
                     const int* __restrict__ rois,
                     float* __restrict__ out)
{
    const int r = blockIdx.x;            // 0..(32*49-1)
    const int b = blockIdx.y;            // 0..15

    const int roi = r / RPB;
    const int s   = 1 + (r % RPB);       // skip s==0 (derived by kernel 2)

    int p, base;
    if (s < 5)       { p = 2; base = 1; }
    else if (s < 14) { p = 3; base = 5; }
    else             { p = 6; base = 14; }
    const int local = s - base;
    const int ix = local / p;
    const int jy = local % p;

    const int rx = __builtin_amdgcn_readfirstlane(rois[roi * 4 + 0]);
    const int ry = __builtin_amdgcn_readfirstlane(rois[roi * 4 + 1]);
    const int rw = __builtin_amdgcn_readfirstlane(rois[roi * 4 + 2]);
    const int rh = __builtin_amdgcn_readfirstlane(rois[roi * 4 + 3]);

    // Reference's axis swap replicated: cl=h/p drives X, rl=w/p drives Y.
    // Python round() == rint (round-half-even) on doubles.
    const double cl = (double)rh / (double)p;
    const double rl = (double)rw / (double)p;
    const double xd = (double)rx;
    const double yd = (double)ry;

    const int x1 = (int)rint(xd + (double)ix * cl);
    const int x2 = (int)rint(xd + (double)ix * cl + cl);
    const int y1 = (int)rint(yd + (double)jy * rl);
    const int y2 = (int)rint(yd + (double)jy * rl + rl);

    const int spanx = x2 - x1;
    const int n = spanx * (y2 - y1);     // >= 1 always

    const int c4 = threadIdx.x;
    const float4* __restrict__ fmb =
        (const float4*)fm + (size_t)b * FH * FW * FC4 + c4;
    const float4* __restrict__ alast =
        fmb + (size_t)((y2 - 1) * FW + (x2 - 1)) * FC4;

    // Slot s0 walks flat indices s0, s0+8, s0+16, ...
    int xs[8], ys[8];
    {
        int xx = x1, yy = y1;
#pragma unroll
        for (int s0 = 0; s0 < 8; ++s0) {
            xs[s0] = xx; ys[s0] = yy;
            if (++xx == x2) { xx = x1; ++yy; }
        }
    }

    const float4 ninf = make_float4(-INFINITY, -INFINITY, -INFINITY, -INFINITY);
    float4 acc[8] = {ninf, ninf, ninf, ninf, ninf, ninf, ninf, ninf};

#define LOAD8_BODY(A0,A1,A2,A3,A4,A5,A6,A7)                                   \
    {                                                                         \
        float4 v0, v1, v2, v3, v4, v5, v6, v7;                                \
        asm volatile(                                                         \
            "global_load_dwordx4 %0, %8, off\n\t"                             \
            "global_load_dwordx4 %1, %9, off\n\t"                             \
            "global_load_dwordx4 %2, %10, off\n\t"                            \
            "global_load_dwordx4 %3, %11, off\n\t"                            \
            "global_load_dwordx4 %4, %12, off\n\t"                            \
            "global_load_dwordx4 %5, %13, off\n\t"                            \
            "global_load_dwordx4 %6, %14, off\n\t"                            \
            "global_load_dwordx4 %7, %15, off\n\t"                            \
            "s_waitcnt vmcnt(0)"                                              \
            : "=&v"(v0), "=&v"(v1), "=&v"(v2), "=&v"(v3),                     \
              "=&v"(v4), "=&v"(v5), "=&v"(v6), "=&v"(v7)                      \
            : "v"(A0), "v"(A1), "v"(A2), "v"(A3),                             \
              "v"(A4), "v"(A5), "v"(A6), "v"(A7));                            \
        acc[0].x = fmaxf(acc[0].x, v0.x); acc[0].y = fmaxf(acc[0].y, v0.y);   \
        acc[0].z = fmaxf(acc[0].z, v0.z); acc[0].w = fmaxf(acc[0].w, v0.w);   \
        acc[1].x = fmaxf(acc[1].x, v1.x); acc[1].y = fmaxf(acc[1].y, v1.y);   \
        acc[1].z = fmaxf(acc[1].z, v1.z); acc[1].w = fmaxf(acc[1].w, v1.w);   \
        acc[2].x = fmaxf(acc[2].x, v2.x); acc[2].y = fmaxf(acc[2].y, v2.y);   \
        acc[2].z = fmaxf(acc[2].z, v2.z); acc[2].w = fmaxf(acc[2].w, v2.w);   \
        acc[3].x = fmaxf(acc[3].x, v3.x); acc[3].y = fmaxf(acc[3].y, v3.y);   \
        acc[3].z = fmaxf(acc[3].z, v3.z); acc[3].w = fmaxf(acc[3].w, v3.w);   \
        acc[4].x = fmaxf(acc[4].x, v4.x); acc[4].y = fmaxf(acc[4].y, v4.y);   \
        acc[4].z = fmaxf(acc[4].z, v4.z); acc[4].w = fmaxf(acc[4].w, v4.w);   \
        acc[5].x = fmaxf(acc[5].x, v5.x); acc[5].y = fmaxf(acc[5].y, v5.y);   \
        acc[5].z = fmaxf(acc[5].z, v5.z); acc[5].w = fmaxf(acc[5].w, v5.w);   \
        acc[6].x = fmaxf(acc[6].x, v6.x); acc[6].y = fmaxf(acc[6].y, v6.y);   \
        acc[6].z = fmaxf(acc[6].z, v6.z); acc[6].w = fmaxf(acc[6].w, v6.w);   \
        acc[7].x = fmaxf(acc[7].x, v7.x); acc[7].y = fmaxf(acc[7].y, v7.y);   \
        acc[7].z = fmaxf(acc[7].z, v7.z); acc[7].w = fmaxf(acc[7].w, v7.w);   \
    }

    int i = 0;
    for (; i + 8 <= n; i += 8) {
        const float4* a[8];
#pragma unroll
        for (int s0 = 0; s0 < 8; ++s0)
            a[s0] = fmb + (size_t)(ys[s0] * FW + xs[s0]) * FC4;

        LOAD8_BODY(a[0], a[1], a[2], a[3], a[4], a[5], a[6], a[7]);

#pragma unroll
        for (int s0 = 0; s0 < 8; ++s0) {
            xs[s0] += 8;
            while (xs[s0] >= x2) { xs[s0] -= spanx; ++ys[s0]; }
        }
    }

    // Tail: same 8-wide asm block; slots past n-1 clamp to the bin's last
    // pixel (redundant max, never OOB).
    if (i < n) {
        const float4* a[8];
#pragma unroll
        for (int s0 = 0; s0 < 8; ++s0) {
            const float4* as = fmb + (size_t)(ys[s0] * FW + xs[s0]) * FC4;
            a[s0] = (i + s0 < n) ? as : alast;
        }
        LOAD8_BODY(a[0], a[1], a[2], a[3], a[4], a[5], a[6], a[7]);
    }
#undef LOAD8_BODY

#pragma unroll
    for (int s0 = 4; s0 < 8; ++s0) {
        acc[s0 - 4].x = fmaxf(acc[s0 - 4].x, acc[s0].x);
        acc[s0 - 4].y = fmaxf(acc[s0 - 4].y, acc[s0].y);
        acc[s0 - 4].z = fmaxf(acc[s0 - 4].z, acc[s0].z);
        acc[s0 - 4].w = fmaxf(acc[s0 - 4].w, acc[s0].w);
    }
    float4 m;
    m.x = fmaxf(fmaxf(acc[0].x, acc[1].x), fmaxf(acc[2].x, acc[3].x));
    m.y = fmaxf(fmaxf(acc[0].y, acc[1].y), fmaxf(acc[2].y, acc[3].y));
    m.z = fmaxf(fmaxf(acc[0].z, acc[1].z), fmaxf(acc[2].z, acc[3].z));
    m.w = fmaxf(fmaxf(acc[0].w, acc[1].w), fmaxf(acc[2].w, acc[3].w));

    float4* out4 = (float4*)out;
    out4[((size_t)b * NREG + roi * REG_PER_ROI + s) * FC4 + c4] = m;
}

// Kernel 2: s==0 (p=1, whole footprint) == max of the four p=2 bins, which
// tile the footprint EXACTLY (h/2, w/2 exact in binary; shared boundaries are
// the identical double expression rint(x+cl)).
__global__ __launch_bounds__(128)
void roi_pool_level0(float* __restrict__ out)
{
    const int roi = blockIdx.x;
    const int b   = blockIdx.y;
    const int c4  = threadIdx.x;

    float4* out4 = (float4*)out;
    const size_t base = ((size_t)b * NREG + roi * REG_PER_ROI) * FC4 + c4;

    float4 a = out4[base + 1 * FC4];
    float4 c = out4[base + 2 * FC4];
    float4 d = out4[base + 3 * FC4];
    float4 e = out4[base + 4 * FC4];

    float4 m;
    m.x = fmaxf(fmaxf(a.x, c.x), fmaxf(d.x, e.x));
    m.y = fmaxf(fmaxf(a.y, c.y), fmaxf(d.y, e.y));
    m.z = fmaxf(fmaxf(a.z, c.z), fmaxf(d.z, e.z));
    m.w = fmaxf(fmaxf(a.w, c.w), fmaxf(d.w, e.w));

    out4[base] = m;
}

extern "C" void kernel_launch(void* const* d_in, const int* in_sizes, int n_in,
                              void* d_out, int out_size, void* d_ws, size_t ws_size,
                              hipStream_t stream) {
    const float* fm   = (const float*)d_in[0];
    const int*   rois = (const int*)d_in[1];
    float*       out  = (float*)d_out;

    dim3 grid1(NUM_ROIS * RPB, FB);
    roi_pool_levels<<<grid1, dim3(128), 0, stream>>>(fm, rois, out);

    dim3 grid2(NUM_ROIS, FB);
    roi_pool_level0<<<grid2, dim3(128), 0, stream>>>(out);
}